// Round 8
// baseline (492.780 us; speedup 1.0000x reference)
//
#include <hip/hip_runtime.h>

#define LRELU(v) ((v) > 0.0f ? (v) : 0.01f * (v))

__device__ __forceinline__ unsigned short f2bf(float f) {
    union { float f; unsigned u; } c;
    c.f = f;
    return (unsigned short)((c.u + 0x7fffu + ((c.u >> 16) & 1)) >> 16);
}
__device__ __forceinline__ float bf_lo(unsigned u) {
    union { unsigned i; float f; } v;
    v.i = u << 16;
    return v.f;
}
__device__ __forceinline__ float bf_hi(unsigned u) {
    union { unsigned i; float f; } v;
    v.i = u & 0xffff0000u;
    return v.f;
}

// ---------------- all four W12 = w1 @ w2 helpers -----------------------------
template <int H2, int HOUT>
__device__ __forceinline__ void w12_body(const float* __restrict__ w1,
                                         const float* __restrict__ w2, float* __restrict__ out,
                                         int i, int o) {
    float s = 0.0f;
#pragma unroll
    for (int k = 0; k < H2; ++k) s += w1[i * H2 + k] * w2[k * HOUT + o];
    out[i * HOUT + o] = s;
}

// ============ dispatch 1: atomic-free bucket counts + w12 + consts ===========
__global__ void count_w12c_k(const int* __restrict__ col, int* __restrict__ bpart, int E, int EB,
                             const float* __restrict__ w1_0, const float* __restrict__ w2_0,
                             float* __restrict__ o0, const float* __restrict__ w1_1,
                             const float* __restrict__ w2_1, float* __restrict__ o1,
                             const float* __restrict__ w1_2, const float* __restrict__ w2_2,
                             float* __restrict__ o2, const float* __restrict__ w1_3,
                             const float* __restrict__ w2_3, float* __restrict__ o3,
                             const float* __restrict__ b1_0, const float* __restrict__ b2_0,
                             const float* __restrict__ b1_1, const float* __restrict__ b2_1,
                             const float* __restrict__ b1_2, const float* __restrict__ b2_2,
                             const float* __restrict__ b1_3, const float* __restrict__ b2_3,
                             const float* __restrict__ fcw, float* __restrict__ cbuf) {
    int b = blockIdx.x;
    int tid = threadIdx.x;  // 1024
    if (b < EB) {
        __shared__ int lcnt[512];
        for (int i = tid; i < 512; i += 1024) lcnt[i] = 0;
        __syncthreads();
        int base = b * 8192;
        for (int k = 0; k < 8; ++k) {
            int e = base + k * 1024 + tid;
            if (e < E) atomicAdd(&lcnt[col[e] >> 7], 1);
        }
        __syncthreads();
        for (int i = tid; i < 512; i += 1024) bpart[(size_t)b * 512 + i] = lcnt[i];
        return;
    }
    int bb = b - EB;
    int o = tid;
    if (bb < 8) {
        if (o < 64) w12_body<128, 64>(w1_0, w2_0, o0, bb, o);
    } else if (bb < 72) {
        if (o < 64) w12_body<128, 64>(w1_1, w2_1, o1, bb - 8, o);
    } else if (bb < 136) {
        if (o < 32) w12_body<64, 32>(w1_2, w2_2, o2, bb - 72, o);
    } else if (bb < 168) {
        if (o < 32) w12_body<64, 32>(w1_3, w2_3, o3, bb - 136, o);
    } else {
        // ---- parallel consts block: 1024 threads, 16 waves ----
        __shared__ float ps[1024];
        __shared__ float c1[64], c2[64], c3[32], c4s[32], u1[128], u2[64], u3[64];
        int t = tid;
        int w = t >> 6;
        float a = 0.0f;
        if (w < 4) {
            int oo = t & 63, g = t >> 6;
#pragma unroll
            for (int j = 0; j < 32; ++j) {
                int k = g * 32 + j;
                a += b1_0[k] * w2_0[k * 64 + oo];
            }
        } else if (w < 8) {
            int oo = t & 63, g = (t >> 6) - 4;
#pragma unroll
            for (int j = 0; j < 32; ++j) {
                int k = g * 32 + j;
                a += b1_1[k] * w2_1[k * 64 + oo];
            }
        } else if (w < 10) {
            int l = t - 512;
            int oo = l & 31, g = l >> 5;
#pragma unroll
            for (int j = 0; j < 16; ++j) {
                int k = g * 16 + j;
                a += b1_2[k] * w2_2[k * 32 + oo];
            }
        } else if (w < 12) {
            int l = t - 640;
            int oo = l & 31, g = l >> 5;
#pragma unroll
            for (int j = 0; j < 16; ++j) {
                int k = g * 16 + j;
                a += b1_3[k] * w2_3[k * 32 + oo];
            }
        }
        ps[t] = a;
        __syncthreads();
        if (t < 64) {
            float raw = ps[t] + ps[t + 64] + ps[t + 128] + ps[t + 192];
            cbuf[192 + t] = raw;
            float c = LRELU(raw + b2_0[t]);
            c1[t] = c;
            cbuf[t] = c;
        } else if (t < 128) {
            int oo = t - 64;
            float raw = ps[256 + oo] + ps[320 + oo] + ps[384 + oo] + ps[448 + oo];
            cbuf[256 + oo] = raw;
            float c = LRELU(raw + b2_1[oo]);
            c2[oo] = c;
            cbuf[64 + oo] = c;
        } else if (t < 160) {
            int oo = t - 128;
            float raw = ps[512 + oo] + ps[544 + oo] + ps[576 + oo] + ps[608 + oo];
            cbuf[384 + oo] = raw;
            float c = LRELU(raw + b2_2[oo]);
            c3[oo] = c;
            cbuf[128 + oo] = c;
        } else if (t < 192) {
            int oo = t - 160;
            float raw = ps[640 + oo] + ps[672 + oo] + ps[704 + oo] + ps[736 + oo];
            cbuf[448 + oo] = raw;
            float c = LRELU(raw + b2_3[oo]);
            c4s[oo] = c;
            cbuf[160 + oo] = c;
        }
        __syncthreads();
        a = 0.0f;
        if (w < 8) {
            int oo = t & 127, g = t >> 7;
#pragma unroll
            for (int j = 0; j < 16; ++j) {
                int f = g * 16 + j;
                a += c1[f] * w1_1[f * 128 + oo];
            }
        } else if (w < 12) {
            int l = t - 512;
            int oo = l & 63, g = l >> 6;
#pragma unroll
            for (int j = 0; j < 16; ++j) {
                int f = g * 16 + j;
                a += c2[f] * w1_2[f * 64 + oo];
            }
        } else {
            int l = t - 768;
            int oo = l & 63, g = l >> 6;
#pragma unroll
            for (int j = 0; j < 8; ++j) {
                int f = g * 8 + j;
                a += c3[f] * w1_3[f * 64 + oo];
            }
        }
        ps[t] = a;
        __syncthreads();
        if (t < 128) {
            u1[t] = ps[t] + ps[t + 128] + ps[t + 256] + ps[t + 384];
        } else if (t < 192) {
            int oo = t - 128;
            u2[oo] = ps[512 + oo] + ps[576 + oo] + ps[640 + oo] + ps[704 + oo];
        } else if (t < 256) {
            int oo = t - 192;
            u3[oo] = ps[768 + oo] + ps[832 + oo] + ps[896 + oo] + ps[960 + oo];
        }
        __syncthreads();
        a = 0.0f;
        if (w < 4) {
            int oo = t & 63, g = t >> 6;
#pragma unroll
            for (int j = 0; j < 32; ++j) {
                int k = g * 32 + j;
                a += u1[k] * w2_1[k * 64 + oo];
            }
        } else if (w < 6) {
            int l = t - 256;
            int oo = l & 31, g = l >> 5;
#pragma unroll
            for (int j = 0; j < 16; ++j) {
                int k = g * 16 + j;
                a += u2[k] * w2_2[k * 32 + oo];
            }
        } else if (w < 8) {
            int l = t - 384;
            int oo = l & 31, g = l >> 5;
#pragma unroll
            for (int j = 0; j < 16; ++j) {
                int k = g * 16 + j;
                a += u3[k] * w2_3[k * 32 + oo];
            }
        }
        ps[t] = a;
        if (w == 8) {
            int l = t - 512;
            float v = (l < 32) ? c4s[l] * fcw[32 + l] : 0.0f;
            v += __shfl_down(v, 16);
            v += __shfl_down(v, 8);
            v += __shfl_down(v, 4);
            v += __shfl_down(v, 2);
            v += __shfl_down(v, 1);
            if (l == 0) cbuf[512] = v;
        }
        __syncthreads();
        if (t < 64) {
            cbuf[320 + t] = cbuf[256 + t] + ps[t] + ps[t + 64] + ps[t + 128] + ps[t + 192];
        } else if (t < 96) {
            int oo = t - 64;
            cbuf[416 + oo] = cbuf[384 + oo] + ps[256 + oo] + ps[288 + oo] + ps[320 + oo] +
                             ps[352 + oo];
        } else if (t < 128) {
            int oo = t - 96;
            cbuf[480 + oo] = cbuf[448 + oo] + ps[384 + oo] + ps[416 + oo] + ps[448 + oo] +
                             ps[480 + oo];
        }
    }
}

// ================= bucket CSR build ==========================================
__global__ void bucket_scan_k(const int* __restrict__ bpart, int* __restrict__ bbase,
                              int* __restrict__ bwp, int NBUCK, int E, int EB) {
    __shared__ int s[512];
    int tid = threadIdx.x;  // 512
    int v = 0;
    if (tid < NBUCK) {
        for (int b = 0; b < EB; ++b) v += bpart[(size_t)b * 512 + tid];
    }
    s[tid] = v;
    __syncthreads();
    for (int off = 1; off < 512; off <<= 1) {
        int t = (tid >= off) ? s[tid - off] : 0;
        __syncthreads();
        s[tid] += t;
        __syncthreads();
    }
    if (tid < NBUCK) {
        int ex = s[tid] - v;
        bbase[tid] = ex;
        bwp[tid] = ex;
    }
    if (tid == 0) bbase[NBUCK] = E;
}

__global__ void bucket_scatter_k(const int* __restrict__ row, const int* __restrict__ col,
                                 int* __restrict__ bwp, int2* __restrict__ tmp, int E) {
    __shared__ int lcnt[512];
    __shared__ int gbase[512];
    int tid = threadIdx.x;  // 1024
    for (int i = tid; i < 512; i += 1024) lcnt[i] = 0;
    __syncthreads();
    int base = blockIdx.x * 8192;
    int lpos[8], bk[8];
    for (int k = 0; k < 8; ++k) {
        int e = base + k * 1024 + tid;
        if (e < E) {
            int b = col[e] >> 7;
            bk[k] = b;
            lpos[k] = atomicAdd(&lcnt[b], 1);
        } else
            bk[k] = -1;
    }
    __syncthreads();
    for (int i = tid; i < 512; i += 1024) {
        int v = lcnt[i];
        gbase[i] = v ? atomicAdd(&bwp[i], v) : 0;
    }
    __syncthreads();
    for (int k = 0; k < 8; ++k) {
        int e = base + k * 1024 + tid;
        if (e < E) {
            int c = col[e];
            tmp[gbase[bk[k]] + lpos[k]] = make_int2(row[e], ((c & 127) << 25) | e);
        }
    }
}

// ---------------- reusable device bodies -------------------------------------
// single-output GEMM body: hl = h@wl (bf16); flat 256-thread block
template <int FIN, int FOUT>
__device__ __forceinline__ void gemmT_body(const float* __restrict__ h,
                                           const float* __restrict__ wl,
                                           unsigned short* __restrict__ hl, int N, int bx,
                                           int tid, float* sw) {
    constexpr int XT = FOUT / 4;
    constexpr int NPT = 4;
    constexpr int NPB = (256 / XT) * NPT;
    int tx = tid % XT, ty = tid / XT;
    for (int idx = tid; idx < FIN * FOUT; idx += 256) sw[idx] = wl[idx];
    __syncthreads();
    int og = tx * 4;
    int base = bx * NPB + ty * NPT;
    int ix[NPT] = {min(base + 0, N - 1), min(base + 1, N - 1), min(base + 2, N - 1),
                   min(base + 3, N - 1)};
    float4 s[NPT] = {{0.f, 0.f, 0.f, 0.f}, {0.f, 0.f, 0.f, 0.f}, {0.f, 0.f, 0.f, 0.f},
                     {0.f, 0.f, 0.f, 0.f}};
#pragma unroll 2
    for (int f = 0; f < FIN; f += 4) {
        float4 w0 = *(const float4*)&sw[(f + 0) * FOUT + og];
        float4 w1 = *(const float4*)&sw[(f + 1) * FOUT + og];
        float4 w2 = *(const float4*)&sw[(f + 2) * FOUT + og];
        float4 w3 = *(const float4*)&sw[(f + 3) * FOUT + og];
#pragma unroll
        for (int k = 0; k < NPT; ++k) {
            float4 v = *(const float4*)(h + (size_t)ix[k] * FIN + f);
            s[k].x += v.x * w0.x + v.y * w1.x + v.z * w2.x + v.w * w3.x;
            s[k].y += v.x * w0.y + v.y * w1.y + v.z * w2.y + v.w * w3.y;
            s[k].z += v.x * w0.z + v.y * w1.z + v.z * w2.z + v.w * w3.z;
            s[k].w += v.x * w0.w + v.y * w1.w + v.z * w2.w + v.w * w3.w;
        }
    }
#pragma unroll
    for (int k = 0; k < NPT; ++k) {
        int i = base + k;
        if (i < N) {
            unsigned short* d = hl + (size_t)i * FOUT + og;
            *(ushort4*)d = make_ushort4(f2bf(s[k].x), f2bf(s[k].y), f2bf(s[k].z), f2bf(s[k].w));
        }
    }
}

#define RED8(off)                                                                   \
    a0 += __shfl_down(a0, off); a1 += __shfl_down(a1, off);                         \
    a2 += __shfl_down(a2, off); a3 += __shfl_down(a3, off);                         \
    a4 += __shfl_down(a4, off); a5 += __shfl_down(a5, off);                         \
    a6 += __shfl_down(a6, off); a7 += __shfl_down(a7, off);

// SAGE aggr 64-wide with FUSED lin_r: wave = 8 rows x 8 lanes (uint4 gathers).
// out = lrelu(mean_gather(T)*inv + h@wr + bl). Per-lane r-partial over
// f-slice [8u,8u+8) x j-slice [8f8,8f8+8); fold inv before the shared reduce.
__device__ __forceinline__ void aggr64_body(const unsigned short* __restrict__ hlb,
                                            const float* __restrict__ h,
                                            const float* __restrict__ wr,
                                            const float* __restrict__ bl,
                                            const int* __restrict__ rowptr,
                                            const int* __restrict__ rows,
                                            float* __restrict__ out, int N, int wave, int lane) {
    if (wave >= N) return;
    int u = lane >> 3, f8 = lane & 7;
    int s = rowptr[wave], e = rowptr[wave + 1];
    // fused lin_r partials (wr reads are L1-resident after first wave)
    float r0 = 0.f, r1 = 0.f, r2 = 0.f, r3 = 0.f, r4 = 0.f, r5 = 0.f, r6 = 0.f, r7 = 0.f;
    {
        const float4* hp = (const float4*)(h + (size_t)wave * 64 + 8 * u);
        float4 hA = hp[0], hB = hp[1];
        float hv0 = hA.x, hv1 = hA.y, hv2 = hA.z, hv3 = hA.w;
        float hv4 = hB.x, hv5 = hB.y, hv6 = hB.z, hv7 = hB.w;
        const float* wrb = wr + (size_t)(8 * u) * 64 + 8 * f8;
#pragma unroll
        for (int t = 0; t < 8; ++t) {
            float4 wA = *(const float4*)(wrb + t * 64);
            float4 wB = *(const float4*)(wrb + t * 64 + 4);
            float hv = (t == 0) ? hv0 : (t == 1) ? hv1 : (t == 2) ? hv2 : (t == 3) ? hv3
                       : (t == 4) ? hv4 : (t == 5) ? hv5 : (t == 6) ? hv6 : hv7;
            r0 += hv * wA.x; r1 += hv * wA.y; r2 += hv * wA.z; r3 += hv * wA.w;
            r4 += hv * wB.x; r5 += hv * wB.y; r6 += hv * wB.z; r7 += hv * wB.w;
        }
    }
    float inv = 1.0f / fmaxf((float)(e - s), 1.0f);
    float a0 = 0.f, a1 = 0.f, a2 = 0.f, a3 = 0.f, a4 = 0.f, a5 = 0.f, a6 = 0.f, a7 = 0.f;
    int p = s + u;
    for (; p + 8 < e; p += 16) {
        int n0 = rows[p], n1 = rows[p + 8];
        uint4 v0 = ((const uint4*)(hlb + (size_t)n0 * 64))[f8];
        uint4 v1 = ((const uint4*)(hlb + (size_t)n1 * 64))[f8];
        a0 += bf_lo(v0.x) + bf_lo(v1.x); a1 += bf_hi(v0.x) + bf_hi(v1.x);
        a2 += bf_lo(v0.y) + bf_lo(v1.y); a3 += bf_hi(v0.y) + bf_hi(v1.y);
        a4 += bf_lo(v0.z) + bf_lo(v1.z); a5 += bf_hi(v0.z) + bf_hi(v1.z);
        a6 += bf_lo(v0.w) + bf_lo(v1.w); a7 += bf_hi(v0.w) + bf_hi(v1.w);
    }
    if (p < e) {
        uint4 v = ((const uint4*)(hlb + (size_t)rows[p] * 64))[f8];
        a0 += bf_lo(v.x); a1 += bf_hi(v.x); a2 += bf_lo(v.y); a3 += bf_hi(v.y);
        a4 += bf_lo(v.z); a5 += bf_hi(v.z); a6 += bf_lo(v.w); a7 += bf_hi(v.w);
    }
    // fold: c = a*inv + r, then one shared reduction tree
    a0 = a0 * inv + r0; a1 = a1 * inv + r1; a2 = a2 * inv + r2; a3 = a3 * inv + r3;
    a4 = a4 * inv + r4; a5 = a5 * inv + r5; a6 = a6 * inv + r6; a7 = a7 * inv + r7;
    RED8(32) RED8(16) RED8(8)
    if (lane < 8) {
        const float4* bp = (const float4*)bl + lane * 2;
        float4 b0 = bp[0], b1 = bp[1];
        float4 o0, o1;
        o0.x = LRELU(a0 + b0.x); o0.y = LRELU(a1 + b0.y);
        o0.z = LRELU(a2 + b0.z); o0.w = LRELU(a3 + b0.w);
        o1.x = LRELU(a4 + b1.x); o1.y = LRELU(a5 + b1.y);
        o1.z = LRELU(a6 + b1.z); o1.w = LRELU(a7 + b1.w);
        float4* op = (float4*)(out + (size_t)wave * 64) + lane * 2;
        op[0] = o0;
        op[1] = o1;
    }
}

// SAGE aggr 32-wide with FUSED lin_r: wave = 16 rows x 4 lanes.
// FIN = width of h (64 for L2, 32 for L3); FOUT = 32.
template <int FIN, bool OUTBF>
__device__ __forceinline__ void aggr32_body(const unsigned short* __restrict__ hlb,
                                            const float* __restrict__ h,
                                            const float* __restrict__ wr,
                                            const float* __restrict__ bl,
                                            const int* __restrict__ rowptr,
                                            const int* __restrict__ rows, void* __restrict__ out,
                                            int N, int wave, int lane) {
    if (wave >= N) return;
    int u = lane >> 2, f8 = lane & 3;
    int s = rowptr[wave], e = rowptr[wave + 1];
    float r0 = 0.f, r1 = 0.f, r2 = 0.f, r3 = 0.f, r4 = 0.f, r5 = 0.f, r6 = 0.f, r7 = 0.f;
    if (FIN == 64) {
        // f-slice [4u,4u+4)
        float4 hA = *(const float4*)(h + (size_t)wave * 64 + 4 * u);
        float hv0 = hA.x, hv1 = hA.y, hv2 = hA.z, hv3 = hA.w;
        const float* wrb = wr + (size_t)(4 * u) * 32 + 8 * f8;
#pragma unroll
        for (int t = 0; t < 4; ++t) {
            float4 wA = *(const float4*)(wrb + t * 32);
            float4 wB = *(const float4*)(wrb + t * 32 + 4);
            float hv = (t == 0) ? hv0 : (t == 1) ? hv1 : (t == 2) ? hv2 : hv3;
            r0 += hv * wA.x; r1 += hv * wA.y; r2 += hv * wA.z; r3 += hv * wA.w;
            r4 += hv * wB.x; r5 += hv * wB.y; r6 += hv * wB.z; r7 += hv * wB.w;
        }
    } else {
        // FIN == 32: f-slice [2u,2u+2)
        float2 hA = *(const float2*)(h + (size_t)wave * 32 + 2 * u);
        float hv0 = hA.x, hv1 = hA.y;
        const float* wrb = wr + (size_t)(2 * u) * 32 + 8 * f8;
#pragma unroll
        for (int t = 0; t < 2; ++t) {
            float4 wA = *(const float4*)(wrb + t * 32);
            float4 wB = *(const float4*)(wrb + t * 32 + 4);
            float hv = (t == 0) ? hv0 : hv1;
            r0 += hv * wA.x; r1 += hv * wA.y; r2 += hv * wA.z; r3 += hv * wA.w;
            r4 += hv * wB.x; r5 += hv * wB.y; r6 += hv * wB.z; r7 += hv * wB.w;
        }
    }
    float inv = 1.0f / fmaxf((float)(e - s), 1.0f);
    float a0 = 0.f, a1 = 0.f, a2 = 0.f, a3 = 0.f, a4 = 0.f, a5 = 0.f, a6 = 0.f, a7 = 0.f;
    int p = s + u;
    for (; p + 16 < e; p += 32) {
        int n0 = rows[p], n1 = rows[p + 16];
        uint4 v0 = ((const uint4*)(hlb + (size_t)n0 * 32))[f8];
        uint4 v1 = ((const uint4*)(hlb + (size_t)n1 * 32))[f8];
        a0 += bf_lo(v0.x) + bf_lo(v1.x); a1 += bf_hi(v0.x) + bf_hi(v1.x);
        a2 += bf_lo(v0.y) + bf_lo(v1.y); a3 += bf_hi(v0.y) + bf_hi(v1.y);
        a4 += bf_lo(v0.z) + bf_lo(v1.z); a5 += bf_hi(v0.z) + bf_hi(v1.z);
        a6 += bf_lo(v0.w) + bf_lo(v1.w); a7 += bf_hi(v0.w) + bf_hi(v1.w);
    }
    if (p < e) {
        uint4 v = ((const uint4*)(hlb + (size_t)rows[p] * 32))[f8];
        a0 += bf_lo(v.x); a1 += bf_hi(v.x); a2 += bf_lo(v.y); a3 += bf_hi(v.y);
        a4 += bf_lo(v.z); a5 += bf_hi(v.z); a6 += bf_lo(v.w); a7 += bf_hi(v.w);
    }
    a0 = a0 * inv + r0; a1 = a1 * inv + r1; a2 = a2 * inv + r2; a3 = a3 * inv + r3;
    a4 = a4 * inv + r4; a5 = a5 * inv + r5; a6 = a6 * inv + r6; a7 = a7 * inv + r7;
    RED8(32) RED8(16) RED8(8) RED8(4)
    if (lane < 4) {
        const float4* bp = (const float4*)bl + lane * 2;
        float4 b0 = bp[0], b1 = bp[1];
        float o0 = LRELU(a0 + b0.x), o1 = LRELU(a1 + b0.y);
        float o2 = LRELU(a2 + b0.z), o3 = LRELU(a3 + b0.w);
        float o4 = LRELU(a4 + b1.x), o5 = LRELU(a5 + b1.y);
        float o6 = LRELU(a6 + b1.z), o7 = LRELU(a7 + b1.w);
        if (OUTBF) {
            unsigned short* d = (unsigned short*)out + (size_t)wave * 32 + lane * 8;
            *(ushort4*)d = make_ushort4(f2bf(o0), f2bf(o1), f2bf(o2), f2bf(o3));
            *(ushort4*)(d + 4) = make_ushort4(f2bf(o4), f2bf(o5), f2bf(o6), f2bf(o7));
        } else {
            float4* op = (float4*)((float*)out + (size_t)wave * 32) + lane * 2;
            op[0] = make_float4(o0, o1, o2, o3);
            op[1] = make_float4(o4, o5, o6, o7);
        }
    }
}

// edge conv layer 0 body: wave = 32 neighbors x 2 f4-lanes; zeroes zbuf (N x 64)
__device__ __forceinline__ void edge_aggr8_body(const float* __restrict__ dis,
                                                const int* __restrict__ rowptr,
                                                const int* __restrict__ eids,
                                                float* __restrict__ sd, float* __restrict__ zbuf,
                                                int N, int wave, int lane) {
    if (wave >= N) return;
    zbuf[(size_t)wave * 64 + lane] = 0.0f;
    int u = lane >> 1, f4 = lane & 1;
    int s = rowptr[wave], e = rowptr[wave + 1];
    float4 a = {0.f, 0.f, 0.f, 0.f};
    for (int p = s + u; p < e; p += 32) {
        const float4* dp = (const float4*)(dis + (size_t)eids[p] * 8);
        float4 v = dp[f4];
        a.x += v.x; a.y += v.y; a.z += v.z; a.w += v.w;
    }
    for (int off = 32; off >= 2; off >>= 1) {
        a.x += __shfl_down(a.x, off); a.y += __shfl_down(a.y, off);
        a.z += __shfl_down(a.z, off); a.w += __shfl_down(a.w, off);
    }
    if (lane < 2) ((float4*)(sd + (size_t)wave * 8))[f4] = a;
}

// collapsed edge conv + delta scatter body; flat 256-thread block
template <int FIN, int FOUT>
__device__ __forceinline__ void esc_body(const float* __restrict__ sd, const int* __restrict__ cnt,
                                         const float* __restrict__ w12,
                                         const float* __restrict__ mw2,
                                         const float* __restrict__ b1w2,
                                         const float* __restrict__ b2,
                                         const float* __restrict__ cnext,
                                         const int* __restrict__ col, float* __restrict__ sdnext,
                                         int N, float* __restrict__ zbuf, int zf4, int bx,
                                         int nblk, int tid, float* sw) {
    constexpr int NPT = 4;
    constexpr int NPB = (256 / FOUT) * NPT;
    int o = tid % FOUT, ty = tid / FOUT;
    for (int idx = tid; idx < FIN * FOUT; idx += 256) sw[idx] = w12[idx];
    __syncthreads();
    if (zf4) {
        float4 z4 = {0.f, 0.f, 0.f, 0.f};
        for (int z = bx * 256 + tid; z < zf4; z += nblk * 256) ((float4*)zbuf)[z] = z4;
    }
    int base = bx * NPB + ty * NPT;
    int ix[NPT] = {min(base + 0, N - 1), min(base + 1, N - 1), min(base + 2, N - 1),
                   min(base + 3, N - 1)};
    float s[NPT] = {0.f, 0.f, 0.f, 0.f};
#pragma unroll 2
    for (int f = 0; f < FIN; f += 4) {
        float w0 = sw[(f + 0) * FOUT + o], w1 = sw[(f + 1) * FOUT + o];
        float w2 = sw[(f + 2) * FOUT + o], w3 = sw[(f + 3) * FOUT + o];
#pragma unroll
        for (int k = 0; k < NPT; ++k) {
            float4 v = *(const float4*)(sd + (size_t)ix[k] * FIN + f);
            s[k] += v.x * w0 + v.y * w1 + v.z * w2 + v.w * w3;
        }
    }
    float mo = mw2[o], bo = b1w2[o], b2o = b2[o], co = cnext[o];
#pragma unroll
    for (int k = 0; k < NPT; ++k) {
        int i = base + k;
        if (i < N) {
            float deg = (float)cnt[i];
            float inv = 1.0f / (deg + 1.0f);
            float val = LRELU((s[k] + deg * mo + bo) * inv + b2o);
            atomicAdd(&sdnext[(size_t)col[i] * FOUT + o], val - co);
        }
    }
}

// last edge conv fused with fc dot body
__device__ __forceinline__ void edot_body(const float* __restrict__ sd,
                                          const int* __restrict__ cnt,
                                          const float* __restrict__ w12,
                                          const float* __restrict__ mw2,
                                          const float* __restrict__ b1w2,
                                          const float* __restrict__ b2,
                                          const float* __restrict__ fcw, float* __restrict__ ddot,
                                          int N, int bx, int tid, float* sw) {
    constexpr int FIN = 32, FOUT = 32;
    constexpr int NPT = 4;
    constexpr int NPB = (256 / FOUT) * NPT;  // 32
    int o = tid % 32, ty = tid / 32;
    for (int idx = tid; idx < FIN * FOUT; idx += 256) sw[idx] = w12[idx];
    __syncthreads();
    int base = bx * NPB + ty * NPT;
    int ix[NPT] = {min(base + 0, N - 1), min(base + 1, N - 1), min(base + 2, N - 1),
                   min(base + 3, N - 1)};
    float s[NPT] = {0.f, 0.f, 0.f, 0.f};
#pragma unroll 2
    for (int f = 0; f < FIN; f += 4) {
        float w0 = sw[(f + 0) * FOUT + o], w1 = sw[(f + 1) * FOUT + o];
        float w2 = sw[(f + 2) * FOUT + o], w3 = sw[(f + 3) * FOUT + o];
#pragma unroll
        for (int k = 0; k < NPT; ++k) {
            float4 v = *(const float4*)(sd + (size_t)ix[k] * FIN + f);
            s[k] += v.x * w0 + v.y * w1 + v.z * w2 + v.w * w3;
        }
    }
    float mo = mw2[o], bo = b1w2[o], b2o = b2[o], fw = fcw[32 + o];
#pragma unroll
    for (int k = 0; k < NPT; ++k) {
        float deg = (float)cnt[ix[k]];
        float inv = 1.0f / (deg + 1.0f);
        float v = LRELU((s[k] + deg * mo + bo) * inv + b2o) * fw;
        v += __shfl_down(v, 16);
        v += __shfl_down(v, 8);
        v += __shfl_down(v, 4);
        v += __shfl_down(v, 2);
        v += __shfl_down(v, 1);
        if (o == 0 && base + k < N) ddot[base + k] = v;
    }
}

// ============ D4: CSR finalize merged with SAGE-L0 gemm (T only) =============
union __align__(16) CsrGemmSM {
    struct {
        int2 buf[3072];
        int lcnt[128];
        int sscan[128];
        int lwp[128];
    } c;
    float sw[64 * 64];
};

__global__ void csr_gemm0_k(const int2* __restrict__ tmp, const int* __restrict__ bbase,
                            int* __restrict__ rowptr, int* __restrict__ cnt,
                            int* __restrict__ rows, int* __restrict__ eids, int N, int E,
                            int NBUCK, const float* __restrict__ h, const float* __restrict__ wl,
                            unsigned short* __restrict__ hl) {
    __shared__ CsrGemmSM sm;
    int tid = threadIdx.x;  // 256
    if (blockIdx.x < NBUCK) {
        constexpr int CAP = 3072;
        int b = blockIdx.x;
        int s = bbase[b], e = bbase[b + 1];
        int sz = e - s;
        if (tid < 128) sm.c.lcnt[tid] = 0;
        __syncthreads();
        for (int i = tid; i < sz; i += 256) {
            int2 v = tmp[s + i];
            if (i < CAP) sm.c.buf[i] = v;
            atomicAdd(&sm.c.lcnt[((unsigned)v.y) >> 25], 1);
        }
        __syncthreads();
        if (tid < 128) sm.c.sscan[tid] = sm.c.lcnt[tid];
        __syncthreads();
        for (int off = 1; off < 128; off <<= 1) {
            int t = (tid < 128 && tid >= off) ? sm.c.sscan[tid - off] : 0;
            __syncthreads();
            if (tid < 128) sm.c.sscan[tid] += t;
            __syncthreads();
        }
        if (tid < 128) {
            int ex = sm.c.sscan[tid] - sm.c.lcnt[tid];
            sm.c.lwp[tid] = ex;
            int c = b * 128 + tid;
            if (c < N) {
                rowptr[c] = s + ex;
                cnt[c] = sm.c.lcnt[tid];
                if (c == N - 1) rowptr[N] = E;
            }
        }
        __syncthreads();
        for (int i = tid; i < sz; i += 256) {
            int2 v = (i < CAP) ? sm.c.buf[i] : tmp[s + i];
            int cl = ((unsigned)v.y) >> 25;
            int p = atomicAdd(&sm.c.lwp[cl], 1);
            rows[s + p] = v.x;
            eids[s + p] = v.y & 0x1FFFFFF;
        }
        return;
    }
    gemmT_body<64, 64>(h, wl, hl, N, blockIdx.x - NBUCK, tid, sm.sw);
}

// ============ D5: SAGE L0 aggr (fused lin_r) ∥ edge_aggr8 ====================
__global__ void ag64_ea8_k(const unsigned short* __restrict__ hlb, const float* __restrict__ h,
                           const float* __restrict__ wr, const float* __restrict__ bl,
                           const int* __restrict__ rowptr, const int* __restrict__ rows,
                           float* __restrict__ out, const float* __restrict__ dis,
                           const int* __restrict__ eids, float* __restrict__ sd0,
                           float* __restrict__ zS1, int N, int NB) {
    int lane = threadIdx.x & 63;
    if (blockIdx.x < NB) {
        int wave = (blockIdx.x * 256 + threadIdx.x) >> 6;
        aggr64_body(hlb, h, wr, bl, rowptr, rows, out, N, wave, lane);
    } else {
        int wave = ((blockIdx.x - NB) * 256 + threadIdx.x) >> 6;
        edge_aggr8_body(dis, rowptr, eids, sd0, zS1, N, wave, lane);
    }
}

// ============ D6: gemm L1 (T only) ∥ esc0 (8->64) ============================
__global__ void g64_esc0_k(const float* __restrict__ h, const float* __restrict__ wl,
                           unsigned short* __restrict__ hl, const float* __restrict__ sd0,
                           const int* __restrict__ cnt, const float* __restrict__ w12,
                           const float* __restrict__ mw2, const float* __restrict__ b1w2,
                           const float* __restrict__ b2, const float* __restrict__ cnext,
                           const int* __restrict__ col, float* __restrict__ S1,
                           float* __restrict__ zS2, int N, int G0, int E0) {
    __shared__ float sw[64 * 64];
    int tid = threadIdx.x;
    if (blockIdx.x < G0) {
        gemmT_body<64, 64>(h, wl, hl, N, blockIdx.x, tid, sw);
    } else {
        esc_body<8, 64>(sd0, cnt, w12, mw2, b1w2, b2, cnext, col, S1, N, zS2, N * 16,
                        blockIdx.x - G0, E0, tid, sw);
    }
}

// ============ D7: SAGE L1 aggr (fused lin_r) ∥ esc1 (64->64) =================
__global__ void ag64_esc1_k(const unsigned short* __restrict__ hlb, const float* __restrict__ h,
                            const float* __restrict__ wr, const float* __restrict__ bl,
                            const int* __restrict__ rowptr, const int* __restrict__ rows,
                            float* __restrict__ out, const float* __restrict__ S1,
                            const int* __restrict__ cnt, const float* __restrict__ w12,
                            const float* __restrict__ mw2, const float* __restrict__ b1w2,
                            const float* __restrict__ b2, const float* __restrict__ cnext,
                            const int* __restrict__ col, float* __restrict__ S2,
                            float* __restrict__ zS3, int N, int NB, int E0) {
    __shared__ float sw[64 * 64];
    int tid = threadIdx.x;
    if (blockIdx.x < NB) {
        int wave = (blockIdx.x * 256 + tid) >> 6;
        aggr64_body(hlb, h, wr, bl, rowptr, rows, out, N, wave, tid & 63);
    } else {
        esc_body<64, 64>(S1, cnt, w12, mw2, b1w2, b2, cnext, col, S2, N, zS3, N * 8,
                         blockIdx.x - NB, E0, tid, sw);
    }
}

// ============ D8: gemm L2 (64->32, T only) ∥ esc2 (64->32) ===================
__global__ void g32_esc2_k(const float* __restrict__ h, const float* __restrict__ wl,
                           unsigned short* __restrict__ hl, const float* __restrict__ S2,
                           const int* __restrict__ cnt, const float* __restrict__ w12,
                           const float* __restrict__ mw2, const float* __restrict__ b1w2,
                           const float* __restrict__ b2, const float* __restrict__ cnext,
                           const int* __restrict__ col, float* __restrict__ S3, int N, int G2,
                           int E2) {
    __shared__ float sw[64 * 32];
    int tid = threadIdx.x;
    if (blockIdx.x < G2) {
        gemmT_body<64, 32>(h, wl, hl, N, blockIdx.x, tid, sw);
    } else {
        esc_body<64, 32>(S2, cnt, w12, mw2, b1w2, b2, cnext, col, S3, N, nullptr, 0,
                         blockIdx.x - G2, E2, tid, sw);
    }
}

// ============ D9: SAGE L2 aggr (fused lin_r, f32 out) ∥ edot =================
__global__ void ag32_edot_k(const unsigned short* __restrict__ hlb, const float* __restrict__ h,
                            const float* __restrict__ wr, const float* __restrict__ bl,
                            const int* __restrict__ rowptr, const int* __restrict__ rows,
                            float* __restrict__ out, const float* __restrict__ S3,
                            const int* __restrict__ cnt, const float* __restrict__ w12,
                            const float* __restrict__ mw2, const float* __restrict__ b1w2,
                            const float* __restrict__ b2, const float* __restrict__ fcw,
                            float* __restrict__ ddot, int N, int NB) {
    __shared__ float sw[32 * 32];
    int tid = threadIdx.x;
    if (blockIdx.x < NB) {
        int wave = (blockIdx.x * 256 + tid) >> 6;
        aggr32_body<64, false>(hlb, h, wr, bl, rowptr, rows, (void*)out, N, wave, tid & 63);
    } else {
        edot_body(S3, cnt, w12, mw2, b1w2, b2, fcw, ddot, N, blockIdx.x - NB, tid, sw);
    }
}

// ============ D10: gemm L3 (32->32, T only) ==================================
__global__ void gemm3_k(const float* __restrict__ h, const float* __restrict__ wl,
                        unsigned short* __restrict__ hl, int N) {
    __shared__ float sw[32 * 32];
    gemmT_body<32, 32>(h, wl, hl, N, blockIdx.x, threadIdx.x, sw);
}

// ============ D11: SAGE L3 aggr (fused lin_r) -> h3b (bf16) ==================
__global__ void ag32bf_k(const unsigned short* __restrict__ hlb, const float* __restrict__ h,
                         const float* __restrict__ wr, const float* __restrict__ bl,
                         const int* __restrict__ rowptr, const int* __restrict__ rows,
                         unsigned short* __restrict__ h3b, int N) {
    int wave = (blockIdx.x * 256 + threadIdx.x) >> 6;
    aggr32_body<32, true>(hlb, h, wr, bl, rowptr, rows, (void*)h3b, N, wave, threadIdx.x & 63);
}

// ============ D12: final, CSR-ordered, uint4 gathers =========================
__global__ void final_csr_k(const unsigned short* __restrict__ h3b,
                            const float* __restrict__ ddot, const float* __restrict__ cbuf,
                            const int* __restrict__ rowptr, const int* __restrict__ rows,
                            const int* __restrict__ eids, const float* __restrict__ fcw,
                            const float* __restrict__ fcb, float* __restrict__ out, int N) {
    int wave = (blockIdx.x * blockDim.x + threadIdx.x) >> 6;
    int lane = threadIdx.x & 63;
    if (wave >= N) return;
    int u = lane >> 2, f2 = lane & 3;
    int s = rowptr[wave], e = rowptr[wave + 1];
    uint4 hc = ((const uint4*)(h3b + (size_t)wave * 32))[f2];
    const float4* fw4 = (const float4*)fcw + f2 * 2;
    float4 w0 = fw4[0], w1 = fw4[1];
    float wc0 = bf_lo(hc.x) * w0.x, wc1 = bf_hi(hc.x) * w0.y;
    float wc2 = bf_lo(hc.y) * w0.z, wc3 = bf_hi(hc.y) * w0.w;
    float wc4 = bf_lo(hc.z) * w1.x, wc5 = bf_hi(hc.z) * w1.y;
    float wc6 = bf_lo(hc.w) * w1.z, wc7 = bf_hi(hc.w) * w1.w;
    float fb = fcb[0];
    float cdot = cbuf[512];
    int p = s + u;
    for (; p + 16 < e; p += 32) {
        int ra = rows[p], rb = rows[p + 16];
        int ea_ = eids[p], eb_ = eids[p + 16];
        uint4 va = ((const uint4*)(h3b + (size_t)ra * 32))[f2];
        uint4 vb = ((const uint4*)(h3b + (size_t)rb * 32))[f2];
        float ta = bf_lo(va.x) * wc0 + bf_hi(va.x) * wc1 + bf_lo(va.y) * wc2 +
                   bf_hi(va.y) * wc3 + bf_lo(va.z) * wc4 + bf_hi(va.z) * wc5 +
                   bf_lo(va.w) * wc6 + bf_hi(va.w) * wc7;
        float tb = bf_lo(vb.x) * wc0 + bf_hi(vb.x) * wc1 + bf_lo(vb.y) * wc2 +
                   bf_hi(vb.y) * wc3 + bf_lo(vb.z) * wc4 + bf_hi(vb.z) * wc5 +
                   bf_lo(vb.w) * wc6 + bf_hi(vb.w) * wc7;
        ta += __shfl_down(ta, 2); tb += __shfl_down(tb, 2);
        ta += __shfl_down(ta, 1); tb += __shfl_down(tb, 1);
        if (f2 == 0) {
            out[ea_] = ta + fb + (ea_ < N ? ddot[ea_] : cdot);
            out[eb_] = tb + fb + (eb_ < N ? ddot[eb_] : cdot);
        }
    }
    if (p < e) {
        int ra = rows[p];
        int ea_ = eids[p];
        uint4 va = ((const uint4*)(h3b + (size_t)ra * 32))[f2];
        float ta = bf_lo(va.x) * wc0 + bf_hi(va.x) * wc1 + bf_lo(va.y) * wc2 +
                   bf_hi(va.y) * wc3 + bf_lo(va.z) * wc4 + bf_hi(va.z) * wc5 +
                   bf_lo(va.w) * wc6 + bf_hi(va.w) * wc7;
        ta += __shfl_down(ta, 2);
        ta += __shfl_down(ta, 1);
        if (f2 == 0) out[ea_] = ta + fb + (ea_ < N ? ddot[ea_] : cdot);
    }
}

extern "C" void kernel_launch(void* const* d_in, const int* in_sizes, int n_in, void* d_out,
                              int out_size, void* d_ws, size_t ws_size, hipStream_t stream) {
    const float* x = (const float*)d_in[0];
    const float* dis = (const float*)d_in[1];
    const int* ei = (const int*)d_in[2];
    const float* s_wl[4] = {(const float*)d_in[3], (const float*)d_in[6], (const float*)d_in[9],
                            (const float*)d_in[12]};
    const float* s_bl[4] = {(const float*)d_in[4], (const float*)d_in[7], (const float*)d_in[10],
                            (const float*)d_in[13]};
    const float* s_wr[4] = {(const float*)d_in[5], (const float*)d_in[8], (const float*)d_in[11],
                            (const float*)d_in[14]};
    const float* e_w1[4] = {(const float*)d_in[15], (const float*)d_in[19], (const float*)d_in[23],
                            (const float*)d_in[27]};
    const float* e_b1[4] = {(const float*)d_in[16], (const float*)d_in[20], (const float*)d_in[24],
                            (const float*)d_in[28]};
    const float* e_w2[4] = {(const float*)d_in[17], (const float*)d_in[21], (const float*)d_in[25],
                            (const float*)d_in[29]};
    const float* e_b2[4] = {(const float*)d_in[18], (const float*)d_in[22], (const float*)d_in[26],
                            (const float*)d_in[30]};
    const float* fcw = (const float*)d_in[31];
    const float* fcb = (const float*)d_in[32];

    const int N = in_sizes[0] / 64;
    const int E = in_sizes[1] / 8;
    const int* row = ei;
    const int* col = ei + E;
    const int NBUCK = (N + 127) / 128;
    const int EB = (E + 8191) / 8192;

    // ---- workspace carve (R buffer removed; lin_r fused into aggr)
    auto au = [](size_t v) { return (v + 255) & ~(size_t)255; };
    char* p = (char*)d_ws;
    int* cnt = (int*)p;        p += au((size_t)N * 4);
    int* rowptr = (int*)p;     p += au((size_t)(N + 1) * 4);
    int* bbase = (int*)p;      p += au(513 * 4);
    int* bwp = (int*)p;        p += au(512 * 4);
    float* w12_0 = (float*)p;  p += au(512 * 4);
    float* w12_1 = (float*)p;  p += au(4096 * 4);
    float* w12_2 = (float*)p;  p += au(2048 * 4);
    float* w12_3 = (float*)p;  p += au(1024 * 4);
    float* cbuf = (float*)p;   p += au(544 * 4);
    int* bpart = (int*)p;      p += au((size_t)EB * 512 * 4);
    int* rowsA = (int*)p;      p += au((size_t)E * 4);
    int* eidsA = (int*)p;      p += au((size_t)E * 4);
    unsigned short* T = (unsigned short*)p; p += au((size_t)N * 64 * 2);  // bf16 hl table
    float* H1 = (float*)p;     p += au((size_t)N * 64 * 4);
    float* H2 = (float*)p;     p += au((size_t)N * 64 * 4);
    float* S1 = (float*)p;     p += au((size_t)N * 64 * 4);               // sd1 (also tmp)
    float* S2 = (float*)p;     p += au((size_t)N * 64 * 4);               // sd2
    float* S3 = (float*)p;     p += au((size_t)N * 32 * 4);               // sd3
    float* sd0 = (float*)p;    p += au((size_t)N * 8 * 4);
    unsigned short* h3b = (unsigned short*)p; p += au((size_t)N * 32 * 2);
    float* ddot = (float*)p;   p += au((size_t)N * 4);

    int2* tmp = (int2*)S1;  // E*8 = 6.4MB <= S1's 12.8MB; tmp dead before S1 first write (D5)

    const int G64 = (N + 63) / 64;    // gemm grids, 64-wide out
    const int G128 = (N + 127) / 128; // gemm grids, 32-wide out
    const int E0 = (N + 15) / 16;
    const int E2 = (N + 31) / 32;
    const int NB = (N + 3) / 4;

    // ---- D1: atomic-free bucket counts + w12 + parallel consts
    count_w12c_k<<<EB + 169, 1024, 0, stream>>>(
        col, bpart, E, EB, e_w1[0], e_w2[0], w12_0, e_w1[1], e_w2[1], w12_1, e_w1[2], e_w2[2],
        w12_2, e_w1[3], e_w2[3], w12_3, e_b1[0], e_b2[0], e_b1[1], e_b2[1], e_b1[2], e_b2[2],
        e_b1[3], e_b2[3], fcw, cbuf);
    // ---- D2-D3: scan + scatter
    bucket_scan_k<<<1, 512, 0, stream>>>(bpart, bbase, bwp, NBUCK, E, EB);
    bucket_scatter_k<<<EB, 1024, 0, stream>>>(row, col, bwp, tmp, E);
    // ---- D4: CSR finalize ∥ SAGE L0 gemm (x -> T)
    csr_gemm0_k<<<NBUCK + G64, 256, 0, stream>>>(tmp, bbase, rowptr, cnt, rowsA, eidsA, N, E,
                                                 NBUCK, x, s_wl[0], T);
    // ---- D5: SAGE L0 aggr+lin_r (T,x -> H1) ∥ edge_aggr8 (dis -> sd0; zero S1)
    ag64_ea8_k<<<2 * NB, 256, 0, stream>>>(T, x, s_wr[0], s_bl[0], rowptr, rowsA, H1, dis, eidsA,
                                           sd0, S1, N, NB);
    // ---- D6: gemm L1 (H1 -> T) ∥ esc0 (sd0 -> scatter S1; zero S2)
    g64_esc0_k<<<G64 + E0, 256, 0, stream>>>(H1, s_wl[1], T, sd0, cnt, w12_0, cbuf + 192,
                                             cbuf + 192, e_b2[0], cbuf + 0, col, S1, S2, N, G64,
                                             E0);
    // ---- D7: SAGE L1 aggr+lin_r (T,H1 -> H2) ∥ esc1 (S1 -> scatter S2; zero S3)
    ag64_esc1_k<<<NB + E0, 256, 0, stream>>>(T, H1, s_wr[1], s_bl[1], rowptr, rowsA, H2, S1, cnt,
                                             w12_1, cbuf + 320, cbuf + 256, e_b2[1], cbuf + 64,
                                             col, S2, S3, N, NB, E0);
    // ---- D8: gemm L2 (H2 -> T 32w) ∥ esc2 (S2 -> scatter S3)
    g32_esc2_k<<<G128 + E2, 256, 0, stream>>>(H2, s_wl[2], T, S2, cnt, w12_2, cbuf + 416,
                                              cbuf + 384, e_b2[2], cbuf + 128, col, S3, N, G128,
                                              E2);
    // ---- D9: SAGE L2 aggr+lin_r (T,H2 -> H1 32w f32) ∥ edot (S3 -> ddot)
    ag32_edot_k<<<NB + E2, 256, 0, stream>>>(T, H2, s_wr[2], s_bl[2], rowptr, rowsA, H1, S3, cnt,
                                             w12_3, cbuf + 480, cbuf + 448, e_b2[3], fcw, ddot,
                                             N, NB);
    // ---- D10: gemm L3 (H1 -> T 32w)
    gemm3_k<<<G128, 256, 0, stream>>>(H1, s_wl[3], T, N);
    // ---- D11: SAGE L3 aggr+lin_r (T,H1 -> h3b bf16)
    ag32bf_k<<<NB, 256, 0, stream>>>(T, H1, s_wr[3], s_bl[3], rowptr, rowsA, h3b, N);
    // ---- D12: final per-edge output, CSR-ordered
    final_csr_k<<<NB, 256, 0, stream>>>(h3b, ddot, cbuf, rowptr, rowsA, eidsA, fcw, fcb,
                                        (float*)d_out, N);
}

// Round 9
// 439.760 us; speedup vs baseline: 1.1206x; 1.1206x over previous
//
#include <hip/hip_runtime.h>

#define LRELU(v) ((v) > 0.0f ? (v) : 0.01f * (v))

__device__ __forceinline__ unsigned short f2bf(float f) {
    union { float f; unsigned u; } c;
    c.f = f;
    return (unsigned short)((c.u + 0x7fffu + ((c.u >> 16) & 1)) >> 16);
}
__device__ __forceinline__ float bf_lo(unsigned u) {
    union { unsigned i; float f; } v;
    v.i = u << 16;
    return v.f;
}
__device__ __forceinline__ float bf_hi(unsigned u) {
    union { unsigned i; float f; } v;
    v.i = u & 0xffff0000u;
    return v.f;
}

// ---------------- all four W12 = w1 @ w2 helpers -----------------------------
template <int H2, int HOUT>
__device__ __forceinline__ void w12_body(const float* __restrict__ w1,
                                         const float* __restrict__ w2, float* __restrict__ out,
                                         int i, int o) {
    float s = 0.0f;
#pragma unroll
    for (int k = 0; k < H2; ++k) s += w1[i * H2 + k] * w2[k * HOUT + o];
    out[i * HOUT + o] = s;
}

// ============ dispatch 1: atomic-free bucket counts + w12 + consts ===========
__global__ void count_w12c_k(const int* __restrict__ col, int* __restrict__ bpart, int E, int EB,
                             const float* __restrict__ w1_0, const float* __restrict__ w2_0,
                             float* __restrict__ o0, const float* __restrict__ w1_1,
                             const float* __restrict__ w2_1, float* __restrict__ o1,
                             const float* __restrict__ w1_2, const float* __restrict__ w2_2,
                             float* __restrict__ o2, const float* __restrict__ w1_3,
                             const float* __restrict__ w2_3, float* __restrict__ o3,
                             const float* __restrict__ b1_0, const float* __restrict__ b2_0,
                             const float* __restrict__ b1_1, const float* __restrict__ b2_1,
                             const float* __restrict__ b1_2, const float* __restrict__ b2_2,
                             const float* __restrict__ b1_3, const float* __restrict__ b2_3,
                             const float* __restrict__ fcw, float* __restrict__ cbuf) {
    int b = blockIdx.x;
    int tid = threadIdx.x;  // 1024
    if (b < EB) {
        __shared__ int lcnt[512];
        for (int i = tid; i < 512; i += 1024) lcnt[i] = 0;
        __syncthreads();
        int base = b * 8192;
        for (int k = 0; k < 8; ++k) {
            int e = base + k * 1024 + tid;
            if (e < E) atomicAdd(&lcnt[col[e] >> 7], 1);
        }
        __syncthreads();
        for (int i = tid; i < 512; i += 1024) bpart[(size_t)b * 512 + i] = lcnt[i];
        return;
    }
    int bb = b - EB;
    int o = tid;
    if (bb < 8) {
        if (o < 64) w12_body<128, 64>(w1_0, w2_0, o0, bb, o);
    } else if (bb < 72) {
        if (o < 64) w12_body<128, 64>(w1_1, w2_1, o1, bb - 8, o);
    } else if (bb < 136) {
        if (o < 32) w12_body<64, 32>(w1_2, w2_2, o2, bb - 72, o);
    } else if (bb < 168) {
        if (o < 32) w12_body<64, 32>(w1_3, w2_3, o3, bb - 136, o);
    } else {
        // ---- parallel consts block: 1024 threads, 16 waves ----
        __shared__ float ps[1024];
        __shared__ float c1[64], c2[64], c3[32], c4s[32], u1[128], u2[64], u3[64];
        int t = tid;
        int w = t >> 6;
        float a = 0.0f;
        if (w < 4) {
            int oo = t & 63, g = t >> 6;
#pragma unroll
            for (int j = 0; j < 32; ++j) {
                int k = g * 32 + j;
                a += b1_0[k] * w2_0[k * 64 + oo];
            }
        } else if (w < 8) {
            int oo = t & 63, g = (t >> 6) - 4;
#pragma unroll
            for (int j = 0; j < 32; ++j) {
                int k = g * 32 + j;
                a += b1_1[k] * w2_1[k * 64 + oo];
            }
        } else if (w < 10) {
            int l = t - 512;
            int oo = l & 31, g = l >> 5;
#pragma unroll
            for (int j = 0; j < 16; ++j) {
                int k = g * 16 + j;
                a += b1_2[k] * w2_2[k * 32 + oo];
            }
        } else if (w < 12) {
            int l = t - 640;
            int oo = l & 31, g = l >> 5;
#pragma unroll
            for (int j = 0; j < 16; ++j) {
                int k = g * 16 + j;
                a += b1_3[k] * w2_3[k * 32 + oo];
            }
        }
        ps[t] = a;
        __syncthreads();
        if (t < 64) {
            float raw = ps[t] + ps[t + 64] + ps[t + 128] + ps[t + 192];
            cbuf[192 + t] = raw;
            float c = LRELU(raw + b2_0[t]);
            c1[t] = c;
            cbuf[t] = c;
        } else if (t < 128) {
            int oo = t - 64;
            float raw = ps[256 + oo] + ps[320 + oo] + ps[384 + oo] + ps[448 + oo];
            cbuf[256 + oo] = raw;
            float c = LRELU(raw + b2_1[oo]);
            c2[oo] = c;
            cbuf[64 + oo] = c;
        } else if (t < 160) {
            int oo = t - 128;
            float raw = ps[512 + oo] + ps[544 + oo] + ps[576 + oo] + ps[608 + oo];
            cbuf[384 + oo] = raw;
            float c = LRELU(raw + b2_2[oo]);
            c3[oo] = c;
            cbuf[128 + oo] = c;
        } else if (t < 192) {
            int oo = t - 160;
            float raw = ps[640 + oo] + ps[672 + oo] + ps[704 + oo] + ps[736 + oo];
            cbuf[448 + oo] = raw;
            float c = LRELU(raw + b2_3[oo]);
            c4s[oo] = c;
            cbuf[160 + oo] = c;
        }
        __syncthreads();
        a = 0.0f;
        if (w < 8) {
            int oo = t & 127, g = t >> 7;
#pragma unroll
            for (int j = 0; j < 16; ++j) {
                int f = g * 16 + j;
                a += c1[f] * w1_1[f * 128 + oo];
            }
        } else if (w < 12) {
            int l = t - 512;
            int oo = l & 63, g = l >> 6;
#pragma unroll
            for (int j = 0; j < 16; ++j) {
                int f = g * 16 + j;
                a += c2[f] * w1_2[f * 64 + oo];
            }
        } else {
            int l = t - 768;
            int oo = l & 63, g = l >> 6;
#pragma unroll
            for (int j = 0; j < 8; ++j) {
                int f = g * 8 + j;
                a += c3[f] * w1_3[f * 64 + oo];
            }
        }
        ps[t] = a;
        __syncthreads();
        if (t < 128) {
            u1[t] = ps[t] + ps[t + 128] + ps[t + 256] + ps[t + 384];
        } else if (t < 192) {
            int oo = t - 128;
            u2[oo] = ps[512 + oo] + ps[576 + oo] + ps[640 + oo] + ps[704 + oo];
        } else if (t < 256) {
            int oo = t - 192;
            u3[oo] = ps[768 + oo] + ps[832 + oo] + ps[896 + oo] + ps[960 + oo];
        }
        __syncthreads();
        a = 0.0f;
        if (w < 4) {
            int oo = t & 63, g = t >> 6;
#pragma unroll
            for (int j = 0; j < 32; ++j) {
                int k = g * 32 + j;
                a += u1[k] * w2_1[k * 64 + oo];
            }
        } else if (w < 6) {
            int l = t - 256;
            int oo = l & 31, g = l >> 5;
#pragma unroll
            for (int j = 0; j < 16; ++j) {
                int k = g * 16 + j;
                a += u2[k] * w2_2[k * 32 + oo];
            }
        } else if (w < 8) {
            int l = t - 384;
            int oo = l & 31, g = l >> 5;
#pragma unroll
            for (int j = 0; j < 16; ++j) {
                int k = g * 16 + j;
                a += u3[k] * w2_3[k * 32 + oo];
            }
        }
        ps[t] = a;
        if (w == 8) {
            int l = t - 512;
            float v = (l < 32) ? c4s[l] * fcw[32 + l] : 0.0f;
            v += __shfl_down(v, 16);
            v += __shfl_down(v, 8);
            v += __shfl_down(v, 4);
            v += __shfl_down(v, 2);
            v += __shfl_down(v, 1);
            if (l == 0) cbuf[512] = v;
        }
        __syncthreads();
        if (t < 64) {
            cbuf[320 + t] = cbuf[256 + t] + ps[t] + ps[t + 64] + ps[t + 128] + ps[t + 192];
        } else if (t < 96) {
            int oo = t - 64;
            cbuf[416 + oo] = cbuf[384 + oo] + ps[256 + oo] + ps[288 + oo] + ps[320 + oo] +
                             ps[352 + oo];
        } else if (t < 128) {
            int oo = t - 96;
            cbuf[480 + oo] = cbuf[448 + oo] + ps[384 + oo] + ps[416 + oo] + ps[448 + oo] +
                             ps[480 + oo];
        }
    }
}

// ================= bucket CSR build ==========================================
__global__ void bucket_scan_k(const int* __restrict__ bpart, int* __restrict__ bbase,
                              int* __restrict__ bwp, int NBUCK, int E, int EB) {
    __shared__ int s[512];
    int tid = threadIdx.x;  // 512
    int v = 0;
    if (tid < NBUCK) {
        for (int b = 0; b < EB; ++b) v += bpart[(size_t)b * 512 + tid];
    }
    s[tid] = v;
    __syncthreads();
    for (int off = 1; off < 512; off <<= 1) {
        int t = (tid >= off) ? s[tid - off] : 0;
        __syncthreads();
        s[tid] += t;
        __syncthreads();
    }
    if (tid < NBUCK) {
        int ex = s[tid] - v;
        bbase[tid] = ex;
        bwp[tid] = ex;
    }
    if (tid == 0) bbase[NBUCK] = E;
}

__global__ void bucket_scatter_k(const int* __restrict__ row, const int* __restrict__ col,
                                 int* __restrict__ bwp, int2* __restrict__ tmp, int E) {
    __shared__ int lcnt[512];
    __shared__ int gbase[512];
    int tid = threadIdx.x;  // 1024
    for (int i = tid; i < 512; i += 1024) lcnt[i] = 0;
    __syncthreads();
    int base = blockIdx.x * 8192;
    int lpos[8], bk[8];
    for (int k = 0; k < 8; ++k) {
        int e = base + k * 1024 + tid;
        if (e < E) {
            int b = col[e] >> 7;
            bk[k] = b;
            lpos[k] = atomicAdd(&lcnt[b], 1);
        } else
            bk[k] = -1;
    }
    __syncthreads();
    for (int i = tid; i < 512; i += 1024) {
        int v = lcnt[i];
        gbase[i] = v ? atomicAdd(&bwp[i], v) : 0;
    }
    __syncthreads();
    for (int k = 0; k < 8; ++k) {
        int e = base + k * 1024 + tid;
        if (e < E) {
            int c = col[e];
            tmp[gbase[bk[k]] + lpos[k]] = make_int2(row[e], ((c & 127) << 25) | e);
        }
    }
}

// ---------------- reusable device bodies -------------------------------------
// dual GEMM body: hl = h@wl (bf16), hr = h@wr + bl; flat 256-thread block
template <int FIN, int FOUT>
__device__ __forceinline__ void gemm2_body(const float* __restrict__ h,
                                           const float* __restrict__ wl,
                                           const float* __restrict__ wr,
                                           const float* __restrict__ bl,
                                           unsigned short* __restrict__ hl,
                                           float* __restrict__ hr, int N, int bx, int tid,
                                           float* sw) {
    constexpr int XT = (2 * FOUT) / 4;
    constexpr int NPT = 4;
    constexpr int NPB = (256 / XT) * NPT;
    int tx = tid % XT, ty = tid / XT;
    for (int idx = tid; idx < FIN * FOUT; idx += 256) {
        int f = idx / FOUT, o = idx % FOUT;
        sw[f * 2 * FOUT + o] = wl[idx];
        sw[f * 2 * FOUT + FOUT + o] = wr[idx];
    }
    __syncthreads();
    int og = tx * 4;
    int base = bx * NPB + ty * NPT;
    int ix[NPT] = {min(base + 0, N - 1), min(base + 1, N - 1), min(base + 2, N - 1),
                   min(base + 3, N - 1)};
    float4 s[NPT] = {{0.f, 0.f, 0.f, 0.f}, {0.f, 0.f, 0.f, 0.f}, {0.f, 0.f, 0.f, 0.f},
                     {0.f, 0.f, 0.f, 0.f}};
#pragma unroll 2
    for (int f = 0; f < FIN; f += 4) {
        float4 w0 = *(const float4*)&sw[(f + 0) * 2 * FOUT + og];
        float4 w1 = *(const float4*)&sw[(f + 1) * 2 * FOUT + og];
        float4 w2 = *(const float4*)&sw[(f + 2) * 2 * FOUT + og];
        float4 w3 = *(const float4*)&sw[(f + 3) * 2 * FOUT + og];
#pragma unroll
        for (int k = 0; k < NPT; ++k) {
            float4 v = *(const float4*)(h + (size_t)ix[k] * FIN + f);
            s[k].x += v.x * w0.x + v.y * w1.x + v.z * w2.x + v.w * w3.x;
            s[k].y += v.x * w0.y + v.y * w1.y + v.z * w2.y + v.w * w3.y;
            s[k].z += v.x * w0.z + v.y * w1.z + v.z * w2.z + v.w * w3.z;
            s[k].w += v.x * w0.w + v.y * w1.w + v.z * w2.w + v.w * w3.w;
        }
    }
    bool isR = og >= FOUT;
    int oo = isR ? og - FOUT : og;
    if (isR) {
        float4 bias = *(const float4*)&bl[oo];
#pragma unroll
        for (int k = 0; k < NPT; ++k) {
            int i = base + k;
            if (i < N) {
                float4 r = {s[k].x + bias.x, s[k].y + bias.y, s[k].z + bias.z, s[k].w + bias.w};
                *(float4*)(hr + (size_t)i * FOUT + oo) = r;
            }
        }
    } else {
#pragma unroll
        for (int k = 0; k < NPT; ++k) {
            int i = base + k;
            if (i < N) {
                unsigned short* d = hl + (size_t)i * FOUT + oo;
                *(ushort4*)d = make_ushort4(f2bf(s[k].x), f2bf(s[k].y), f2bf(s[k].z), f2bf(s[k].w));
            }
        }
    }
}

#define RED8(off)                                                                   \
    a0 += __shfl_down(a0, off); a1 += __shfl_down(a1, off);                         \
    a2 += __shfl_down(a2, off); a3 += __shfl_down(a3, off);                         \
    a4 += __shfl_down(a4, off); a5 += __shfl_down(a5, off);                         \
    a6 += __shfl_down(a6, off); a7 += __shfl_down(a7, off);

// SAGE aggr 64-wide body: wave = 8 rows x 8 lanes (uint4 = 8 bf16), 2-deep
// hr epilogue operands are prefetched BEFORE the gather loop (latency hiding).
__device__ __forceinline__ void aggr64_body(const unsigned short* __restrict__ hlb,
                                            const float* __restrict__ hr,
                                            const int* __restrict__ rowptr,
                                            const int* __restrict__ rows,
                                            float* __restrict__ out, int N, int wave, int lane) {
    if (wave >= N) return;
    int u = lane >> 3, f8 = lane & 7;
    int s = rowptr[wave], e = rowptr[wave + 1];
    // prefetch epilogue operands (clamped lane -> in-bounds for all 64 lanes)
    int l8 = lane & 7;
    const float4* hp = (const float4*)(hr + (size_t)wave * 64) + l8 * 2;
    float4 r0h = hp[0], r1h = hp[1];
    float inv = 1.0f / fmaxf((float)(e - s), 1.0f);
    float a0 = 0.f, a1 = 0.f, a2 = 0.f, a3 = 0.f, a4 = 0.f, a5 = 0.f, a6 = 0.f, a7 = 0.f;
    int p = s + u;
    for (; p + 8 < e; p += 16) {
        int r0 = rows[p], r1 = rows[p + 8];
        uint4 v0 = ((const uint4*)(hlb + (size_t)r0 * 64))[f8];
        uint4 v1 = ((const uint4*)(hlb + (size_t)r1 * 64))[f8];
        a0 += bf_lo(v0.x) + bf_lo(v1.x); a1 += bf_hi(v0.x) + bf_hi(v1.x);
        a2 += bf_lo(v0.y) + bf_lo(v1.y); a3 += bf_hi(v0.y) + bf_hi(v1.y);
        a4 += bf_lo(v0.z) + bf_lo(v1.z); a5 += bf_hi(v0.z) + bf_hi(v1.z);
        a6 += bf_lo(v0.w) + bf_lo(v1.w); a7 += bf_hi(v0.w) + bf_hi(v1.w);
    }
    if (p < e) {
        uint4 v = ((const uint4*)(hlb + (size_t)rows[p] * 64))[f8];
        a0 += bf_lo(v.x); a1 += bf_hi(v.x); a2 += bf_lo(v.y); a3 += bf_hi(v.y);
        a4 += bf_lo(v.z); a5 += bf_hi(v.z); a6 += bf_lo(v.w); a7 += bf_hi(v.w);
    }
    RED8(32) RED8(16) RED8(8)
    if (lane < 8) {
        float4 o0, o1;
        o0.x = LRELU(a0 * inv + r0h.x); o0.y = LRELU(a1 * inv + r0h.y);
        o0.z = LRELU(a2 * inv + r0h.z); o0.w = LRELU(a3 * inv + r0h.w);
        o1.x = LRELU(a4 * inv + r1h.x); o1.y = LRELU(a5 * inv + r1h.y);
        o1.z = LRELU(a6 * inv + r1h.z); o1.w = LRELU(a7 * inv + r1h.w);
        float4* op = (float4*)(out + (size_t)wave * 64) + lane * 2;
        op[0] = o0;
        op[1] = o1;
    }
}

// SAGE aggr 32-wide body: wave = 16 rows x 4 lanes (uint4 = 8 bf16), 2-deep
template <bool OUTBF>
__device__ __forceinline__ void aggr32_body(const unsigned short* __restrict__ hlb,
                                            const float* __restrict__ hr,
                                            const int* __restrict__ rowptr,
                                            const int* __restrict__ rows, void* __restrict__ out,
                                            int N, int wave, int lane) {
    if (wave >= N) return;
    int u = lane >> 2, f8 = lane & 3;
    int s = rowptr[wave], e = rowptr[wave + 1];
    // prefetch epilogue operands (clamped lane -> in-bounds)
    int l4 = lane & 3;
    const float4* hp = (const float4*)(hr + (size_t)wave * 32) + l4 * 2;
    float4 r0h = hp[0], r1h = hp[1];
    float inv = 1.0f / fmaxf((float)(e - s), 1.0f);
    float a0 = 0.f, a1 = 0.f, a2 = 0.f, a3 = 0.f, a4 = 0.f, a5 = 0.f, a6 = 0.f, a7 = 0.f;
    int p = s + u;
    for (; p + 16 < e; p += 32) {
        int r0 = rows[p], r1 = rows[p + 16];
        uint4 v0 = ((const uint4*)(hlb + (size_t)r0 * 32))[f8];
        uint4 v1 = ((const uint4*)(hlb + (size_t)r1 * 32))[f8];
        a0 += bf_lo(v0.x) + bf_lo(v1.x); a1 += bf_hi(v0.x) + bf_hi(v1.x);
        a2 += bf_lo(v0.y) + bf_lo(v1.y); a3 += bf_hi(v0.y) + bf_hi(v1.y);
        a4 += bf_lo(v0.z) + bf_lo(v1.z); a5 += bf_hi(v0.z) + bf_hi(v1.z);
        a6 += bf_lo(v0.w) + bf_lo(v1.w); a7 += bf_hi(v0.w) + bf_hi(v1.w);
    }
    if (p < e) {
        uint4 v = ((const uint4*)(hlb + (size_t)rows[p] * 32))[f8];
        a0 += bf_lo(v.x); a1 += bf_hi(v.x); a2 += bf_lo(v.y); a3 += bf_hi(v.y);
        a4 += bf_lo(v.z); a5 += bf_hi(v.z); a6 += bf_lo(v.w); a7 += bf_hi(v.w);
    }
    RED8(32) RED8(16) RED8(8) RED8(4)
    if (lane < 4) {
        float o0 = LRELU(a0 * inv + r0h.x), o1 = LRELU(a1 * inv + r0h.y);
        float o2 = LRELU(a2 * inv + r0h.z), o3 = LRELU(a3 * inv + r0h.w);
        float o4 = LRELU(a4 * inv + r1h.x), o5 = LRELU(a5 * inv + r1h.y);
        float o6 = LRELU(a6 * inv + r1h.z), o7 = LRELU(a7 * inv + r1h.w);
        if (OUTBF) {
            unsigned short* d = (unsigned short*)out + (size_t)wave * 32 + lane * 8;
            *(ushort4*)d = make_ushort4(f2bf(o0), f2bf(o1), f2bf(o2), f2bf(o3));
            *(ushort4*)(d + 4) = make_ushort4(f2bf(o4), f2bf(o5), f2bf(o6), f2bf(o7));
        } else {
            float4* op = (float4*)((float*)out + (size_t)wave * 32) + lane * 2;
            op[0] = make_float4(o0, o1, o2, o3);
            op[1] = make_float4(o4, o5, o6, o7);
        }
    }
}

// edge conv layer 0 body: wave = 32 neighbors x 2 f4-lanes; zeroes zbuf (N x 64)
__device__ __forceinline__ void edge_aggr8_body(const float* __restrict__ dis,
                                                const int* __restrict__ rowptr,
                                                const int* __restrict__ eids,
                                                float* __restrict__ sd, float* __restrict__ zbuf,
                                                int N, int wave, int lane) {
    if (wave >= N) return;
    zbuf[(size_t)wave * 64 + lane] = 0.0f;
    int u = lane >> 1, f4 = lane & 1;
    int s = rowptr[wave], e = rowptr[wave + 1];
    float4 a = {0.f, 0.f, 0.f, 0.f};
    for (int p = s + u; p < e; p += 32) {
        const float4* dp = (const float4*)(dis + (size_t)eids[p] * 8);
        float4 v = dp[f4];
        a.x += v.x; a.y += v.y; a.z += v.z; a.w += v.w;
    }
    for (int off = 32; off >= 2; off >>= 1) {
        a.x += __shfl_down(a.x, off); a.y += __shfl_down(a.y, off);
        a.z += __shfl_down(a.z, off); a.w += __shfl_down(a.w, off);
    }
    if (lane < 2) ((float4*)(sd + (size_t)wave * 8))[f4] = a;
}

// collapsed edge conv + delta scatter body; flat 256-thread block
template <int FIN, int FOUT>
__device__ __forceinline__ void esc_body(const float* __restrict__ sd, const int* __restrict__ cnt,
                                         const float* __restrict__ w12,
                                         const float* __restrict__ mw2,
                                         const float* __restrict__ b1w2,
                                         const float* __restrict__ b2,
                                         const float* __restrict__ cnext,
                                         const int* __restrict__ col, float* __restrict__ sdnext,
                                         int N, float* __restrict__ zbuf, int zf4, int bx,
                                         int nblk, int tid, float* sw) {
    constexpr int NPT = 4;
    constexpr int NPB = (256 / FOUT) * NPT;
    int o = tid % FOUT, ty = tid / FOUT;
    for (int idx = tid; idx < FIN * FOUT; idx += 256) sw[idx] = w12[idx];
    __syncthreads();
    if (zf4) {
        float4 z4 = {0.f, 0.f, 0.f, 0.f};
        for (int z = bx * 256 + tid; z < zf4; z += nblk * 256) ((float4*)zbuf)[z] = z4;
    }
    int base = bx * NPB + ty * NPT;
    int ix[NPT] = {min(base + 0, N - 1), min(base + 1, N - 1), min(base + 2, N - 1),
                   min(base + 3, N - 1)};
    float s[NPT] = {0.f, 0.f, 0.f, 0.f};
#pragma unroll 2
    for (int f = 0; f < FIN; f += 4) {
        float w0 = sw[(f + 0) * FOUT + o], w1 = sw[(f + 1) * FOUT + o];
        float w2 = sw[(f + 2) * FOUT + o], w3 = sw[(f + 3) * FOUT + o];
#pragma unroll
        for (int k = 0; k < NPT; ++k) {
            float4 v = *(const float4*)(sd + (size_t)ix[k] * FIN + f);
            s[k] += v.x * w0 + v.y * w1 + v.z * w2 + v.w * w3;
        }
    }
    float mo = mw2[o], bo = b1w2[o], b2o = b2[o], co = cnext[o];
#pragma unroll
    for (int k = 0; k < NPT; ++k) {
        int i = base + k;
        if (i < N) {
            float deg = (float)cnt[i];
            float inv = 1.0f / (deg + 1.0f);
            float val = LRELU((s[k] + deg * mo + bo) * inv + b2o);
            atomicAdd(&sdnext[(size_t)col[i] * FOUT + o], val - co);
        }
    }
}

// last edge conv fused with fc dot body
__device__ __forceinline__ void edot_body(const float* __restrict__ sd,
                                          const int* __restrict__ cnt,
                                          const float* __restrict__ w12,
                                          const float* __restrict__ mw2,
                                          const float* __restrict__ b1w2,
                                          const float* __restrict__ b2,
                                          const float* __restrict__ fcw, float* __restrict__ ddot,
                                          int N, int bx, int tid, float* sw) {
    constexpr int FIN = 32, FOUT = 32;
    constexpr int NPT = 4;
    constexpr int NPB = (256 / FOUT) * NPT;  // 32
    int o = tid % 32, ty = tid / 32;
    for (int idx = tid; idx < FIN * FOUT; idx += 256) sw[idx] = w12[idx];
    __syncthreads();
    int base = bx * NPB + ty * NPT;
    int ix[NPT] = {min(base + 0, N - 1), min(base + 1, N - 1), min(base + 2, N - 1),
                   min(base + 3, N - 1)};
    float s[NPT] = {0.f, 0.f, 0.f, 0.f};
#pragma unroll 2
    for (int f = 0; f < FIN; f += 4) {
        float w0 = sw[(f + 0) * FOUT + o], w1 = sw[(f + 1) * FOUT + o];
        float w2 = sw[(f + 2) * FOUT + o], w3 = sw[(f + 3) * FOUT + o];
#pragma unroll
        for (int k = 0; k < NPT; ++k) {
            float4 v = *(const float4*)(sd + (size_t)ix[k] * FIN + f);
            s[k] += v.x * w0 + v.y * w1 + v.z * w2 + v.w * w3;
        }
    }
    float mo = mw2[o], bo = b1w2[o], b2o = b2[o], fw = fcw[32 + o];
#pragma unroll
    for (int k = 0; k < NPT; ++k) {
        float deg = (float)cnt[ix[k]];
        float inv = 1.0f / (deg + 1.0f);
        float v = LRELU((s[k] + deg * mo + bo) * inv + b2o) * fw;
        v += __shfl_down(v, 16);
        v += __shfl_down(v, 8);
        v += __shfl_down(v, 4);
        v += __shfl_down(v, 2);
        v += __shfl_down(v, 1);
        if (o == 0 && base + k < N) ddot[base + k] = v;
    }
}

// ============ D4: CSR finalize merged with SAGE-L0 dual GEMM =================
// CAP 3072: buckets hold E/NBUCK ~= 2046 entries (max ~2210); union 32 KB ->
// 5 blocks/CU. Overflow path (re-read tmp) retained for safety.
union __align__(16) CsrGemmSM {
    struct {
        int2 buf[3072];
        int lcnt[128];
        int sscan[128];
        int lwp[128];
    } c;
    float sw[64 * 128];
};

__global__ void csr_gemm0_k(const int2* __restrict__ tmp, const int* __restrict__ bbase,
                            int* __restrict__ rowptr, int* __restrict__ cnt,
                            int* __restrict__ rows, int* __restrict__ eids, int N, int E,
                            int NBUCK, const float* __restrict__ h, const float* __restrict__ wl,
                            const float* __restrict__ wr, const float* __restrict__ bl,
                            unsigned short* __restrict__ hl, float* __restrict__ hr) {
    __shared__ CsrGemmSM sm;
    int tid = threadIdx.x;  // 256
    if (blockIdx.x < NBUCK) {
        constexpr int CAP = 3072;
        int b = blockIdx.x;
        int s = bbase[b], e = bbase[b + 1];
        int sz = e - s;
        if (tid < 128) sm.c.lcnt[tid] = 0;
        __syncthreads();
        for (int i = tid; i < sz; i += 256) {
            int2 v = tmp[s + i];
            if (i < CAP) sm.c.buf[i] = v;
            atomicAdd(&sm.c.lcnt[((unsigned)v.y) >> 25], 1);
        }
        __syncthreads();
        if (tid < 128) sm.c.sscan[tid] = sm.c.lcnt[tid];
        __syncthreads();
        for (int off = 1; off < 128; off <<= 1) {
            int t = (tid < 128 && tid >= off) ? sm.c.sscan[tid - off] : 0;
            __syncthreads();
            if (tid < 128) sm.c.sscan[tid] += t;
            __syncthreads();
        }
        if (tid < 128) {
            int ex = sm.c.sscan[tid] - sm.c.lcnt[tid];
            sm.c.lwp[tid] = ex;
            int c = b * 128 + tid;
            if (c < N) {
                rowptr[c] = s + ex;
                cnt[c] = sm.c.lcnt[tid];
                if (c == N - 1) rowptr[N] = E;
            }
        }
        __syncthreads();
        for (int i = tid; i < sz; i += 256) {
            int2 v = (i < CAP) ? sm.c.buf[i] : tmp[s + i];
            int cl = ((unsigned)v.y) >> 25;
            int p = atomicAdd(&sm.c.lwp[cl], 1);
            rows[s + p] = v.x;
            eids[s + p] = v.y & 0x1FFFFFF;
        }
        return;
    }
    gemm2_body<64, 64>(h, wl, wr, bl, hl, hr, N, blockIdx.x - NBUCK, tid, sm.sw);
}

// ============ D5: SAGE L0 aggr ∥ edge_aggr8 ==================================
__global__ void ag64_ea8_k(const unsigned short* __restrict__ hlb, const float* __restrict__ hr,
                           const int* __restrict__ rowptr, const int* __restrict__ rows,
                           float* __restrict__ out, const float* __restrict__ dis,
                           const int* __restrict__ eids, float* __restrict__ sd0,
                           float* __restrict__ zS1, int N, int NB) {
    int lane = threadIdx.x & 63;
    if (blockIdx.x < NB) {
        int wave = (blockIdx.x * 256 + threadIdx.x) >> 6;
        aggr64_body(hlb, hr, rowptr, rows, out, N, wave, lane);
    } else {
        int wave = ((blockIdx.x - NB) * 256 + threadIdx.x) >> 6;
        edge_aggr8_body(dis, rowptr, eids, sd0, zS1, N, wave, lane);
    }
}

// ============ D6: gemm L1 ∥ esc0 (8->64) =====================================
__global__ void g64_esc0_k(const float* __restrict__ h, const float* __restrict__ wl,
                           const float* __restrict__ wr, const float* __restrict__ bl,
                           unsigned short* __restrict__ hl, float* __restrict__ hr,
                           const float* __restrict__ sd0, const int* __restrict__ cnt,
                           const float* __restrict__ w12, const float* __restrict__ mw2,
                           const float* __restrict__ b1w2, const float* __restrict__ b2,
                           const float* __restrict__ cnext, const int* __restrict__ col,
                           float* __restrict__ S1, float* __restrict__ zS2, int N, int G0,
                           int E0) {
    __shared__ float sw[64 * 128];
    int tid = threadIdx.x;
    if (blockIdx.x < G0) {
        gemm2_body<64, 64>(h, wl, wr, bl, hl, hr, N, blockIdx.x, tid, sw);
    } else {
        esc_body<8, 64>(sd0, cnt, w12, mw2, b1w2, b2, cnext, col, S1, N, zS2, N * 16,
                        blockIdx.x - G0, E0, tid, sw);
    }
}

// ============ D7: SAGE L1 aggr ∥ esc1 (64->64) ===============================
__global__ void ag64_esc1_k(const unsigned short* __restrict__ hlb, const float* __restrict__ hr,
                            const int* __restrict__ rowptr, const int* __restrict__ rows,
                            float* __restrict__ out, const float* __restrict__ S1,
                            const int* __restrict__ cnt, const float* __restrict__ w12,
                            const float* __restrict__ mw2, const float* __restrict__ b1w2,
                            const float* __restrict__ b2, const float* __restrict__ cnext,
                            const int* __restrict__ col, float* __restrict__ S2,
                            float* __restrict__ zS3, int N, int NB, int E0) {
    __shared__ float sw[64 * 64];
    int tid = threadIdx.x;
    if (blockIdx.x < NB) {
        int wave = (blockIdx.x * 256 + tid) >> 6;
        aggr64_body(hlb, hr, rowptr, rows, out, N, wave, tid & 63);
    } else {
        esc_body<64, 64>(S1, cnt, w12, mw2, b1w2, b2, cnext, col, S2, N, zS3, N * 8,
                         blockIdx.x - NB, E0, tid, sw);
    }
}

// ============ D8: gemm L2 (64->32) ∥ esc2 (64->32) ===========================
__global__ void g32_esc2_k(const float* __restrict__ h, const float* __restrict__ wl,
                           const float* __restrict__ wr, const float* __restrict__ bl,
                           unsigned short* __restrict__ hl, float* __restrict__ hr,
                           const float* __restrict__ S2, const int* __restrict__ cnt,
                           const float* __restrict__ w12, const float* __restrict__ mw2,
                           const float* __restrict__ b1w2, const float* __restrict__ b2,
                           const float* __restrict__ cnext, const int* __restrict__ col,
                           float* __restrict__ S3, int N, int G2, int E2) {
    __shared__ float sw[64 * 64];
    int tid = threadIdx.x;
    if (blockIdx.x < G2) {
        gemm2_body<64, 32>(h, wl, wr, bl, hl, hr, N, blockIdx.x, tid, sw);
    } else {
        esc_body<64, 32>(S2, cnt, w12, mw2, b1w2, b2, cnext, col, S3, N, nullptr, 0,
                         blockIdx.x - G2, E2, tid, sw);
    }
}

// ============ D9: SAGE L2 aggr (f32 out) ∥ edot ==============================
__global__ void ag32_edot_k(const unsigned short* __restrict__ hlb, const float* __restrict__ hr,
                            const int* __restrict__ rowptr, const int* __restrict__ rows,
                            float* __restrict__ out, const float* __restrict__ S3,
                            const int* __restrict__ cnt, const float* __restrict__ w12,
                            const float* __restrict__ mw2, const float* __restrict__ b1w2,
                            const float* __restrict__ b2, const float* __restrict__ fcw,
                            float* __restrict__ ddot, int N, int NB) {
    __shared__ float sw[32 * 32];
    int tid = threadIdx.x;
    if (blockIdx.x < NB) {
        int wave = (blockIdx.x * 256 + tid) >> 6;
        aggr32_body<false>(hlb, hr, rowptr, rows, (void*)out, N, wave, tid & 63);
    } else {
        edot_body(S3, cnt, w12, mw2, b1w2, b2, fcw, ddot, N, blockIdx.x - NB, tid, sw);
    }
}

// ============ D10: gemm L3 (32->32) ==========================================
__global__ void gemm2_32_k(const float* __restrict__ h, const float* __restrict__ wl,
                           const float* __restrict__ wr, const float* __restrict__ bl,
                           unsigned short* __restrict__ hl, float* __restrict__ hr, int N) {
    __shared__ float sw[32 * 64];
    gemm2_body<32, 32>(h, wl, wr, bl, hl, hr, N, blockIdx.x, threadIdx.x, sw);
}

// ============ D11: SAGE L3 aggr -> h3b (bf16) ================================
__global__ void ag32bf_k(const unsigned short* __restrict__ hlb, const float* __restrict__ hr,
                         const int* __restrict__ rowptr, const int* __restrict__ rows,
                         unsigned short* __restrict__ h3b, int N) {
    int wave = (blockIdx.x * 256 + threadIdx.x) >> 6;
    aggr32_body<true>(hlb, hr, rowptr, rows, (void*)h3b, N, wave, threadIdx.x & 63);
}

// ============ D12: final, CSR-ordered, uint4 gathers =========================
// wave = node (segment); 16 edges x 4 lanes (uint4 = 8 bf16 each); 2-deep.
__global__ void final_csr_k(const unsigned short* __restrict__ h3b,
                            const float* __restrict__ ddot, const float* __restrict__ cbuf,
                            const int* __restrict__ rowptr, const int* __restrict__ rows,
                            const int* __restrict__ eids, const float* __restrict__ fcw,
                            const float* __restrict__ fcb, float* __restrict__ out, int N) {
    int wave = (blockIdx.x * blockDim.x + threadIdx.x) >> 6;
    int lane = threadIdx.x & 63;
    if (wave >= N) return;
    int u = lane >> 2, f2 = lane & 3;
    int s = rowptr[wave], e = rowptr[wave + 1];
    uint4 hc = ((const uint4*)(h3b + (size_t)wave * 32))[f2];
    const float4* fw4 = (const float4*)fcw + f2 * 2;
    float4 w0 = fw4[0], w1 = fw4[1];
    float wc0 = bf_lo(hc.x) * w0.x, wc1 = bf_hi(hc.x) * w0.y;
    float wc2 = bf_lo(hc.y) * w0.z, wc3 = bf_hi(hc.y) * w0.w;
    float wc4 = bf_lo(hc.z) * w1.x, wc5 = bf_hi(hc.z) * w1.y;
    float wc6 = bf_lo(hc.w) * w1.z, wc7 = bf_hi(hc.w) * w1.w;
    float fb = fcb[0];
    float cdot = cbuf[512];
    int p = s + u;
    for (; p + 16 < e; p += 32) {
        int ra = rows[p], rb = rows[p + 16];
        int ea_ = eids[p], eb_ = eids[p + 16];
        uint4 va = ((const uint4*)(h3b + (size_t)ra * 32))[f2];
        uint4 vb = ((const uint4*)(h3b + (size_t)rb * 32))[f2];
        float ta = bf_lo(va.x) * wc0 + bf_hi(va.x) * wc1 + bf_lo(va.y) * wc2 +
                   bf_hi(va.y) * wc3 + bf_lo(va.z) * wc4 + bf_hi(va.z) * wc5 +
                   bf_lo(va.w) * wc6 + bf_hi(va.w) * wc7;
        float tb = bf_lo(vb.x) * wc0 + bf_hi(vb.x) * wc1 + bf_lo(vb.y) * wc2 +
                   bf_hi(vb.y) * wc3 + bf_lo(vb.z) * wc4 + bf_hi(vb.z) * wc5 +
                   bf_lo(vb.w) * wc6 + bf_hi(vb.w) * wc7;
        ta += __shfl_down(ta, 2); tb += __shfl_down(tb, 2);
        ta += __shfl_down(ta, 1); tb += __shfl_down(tb, 1);
        if (f2 == 0) {
            out[ea_] = ta + fb + (ea_ < N ? ddot[ea_] : cdot);
            out[eb_] = tb + fb + (eb_ < N ? ddot[eb_] : cdot);
        }
    }
    if (p < e) {
        int ra = rows[p];
        int ea_ = eids[p];
        uint4 va = ((const uint4*)(h3b + (size_t)ra * 32))[f2];
        float ta = bf_lo(va.x) * wc0 + bf_hi(va.x) * wc1 + bf_lo(va.y) * wc2 +
                   bf_hi(va.y) * wc3 + bf_lo(va.z) * wc4 + bf_hi(va.z) * wc5 +
                   bf_lo(va.w) * wc6 + bf_hi(va.w) * wc7;
        ta += __shfl_down(ta, 2);
        ta += __shfl_down(ta, 1);
        if (f2 == 0) out[ea_] = ta + fb + (ea_ < N ? ddot[ea_] : cdot);
    }
}

extern "C" void kernel_launch(void* const* d_in, const int* in_sizes, int n_in, void* d_out,
                              int out_size, void* d_ws, size_t ws_size, hipStream_t stream) {
    const float* x = (const float*)d_in[0];
    const float* dis = (const float*)d_in[1];
    const int* ei = (const int*)d_in[2];
    const float* s_wl[4] = {(const float*)d_in[3], (const float*)d_in[6], (const float*)d_in[9],
                            (const float*)d_in[12]};
    const float* s_bl[4] = {(const float*)d_in[4], (const float*)d_in[7], (const float*)d_in[10],
                            (const float*)d_in[13]};
    const float* s_wr[4] = {(const float*)d_in[5], (const float*)d_in[8], (const float*)d_in[11],
                            (const float*)d_in[14]};
    const float* e_w1[4] = {(const float*)d_in[15], (const float*)d_in[19], (const float*)d_in[23],
                            (const float*)d_in[27]};
    const float* e_b1[4] = {(const float*)d_in[16], (const float*)d_in[20], (const float*)d_in[24],
                            (const float*)d_in[28]};
    const float* e_w2[4] = {(const float*)d_in[17], (const float*)d_in[21], (const float*)d_in[25],
                            (const float*)d_in[29]};
    const float* e_b2[4] = {(const float*)d_in[18], (const float*)d_in[22], (const float*)d_in[26],
                            (const float*)d_in[30]};
    const float* fcw = (const float*)d_in[31];
    const float* fcb = (const float*)d_in[32];

    const int N = in_sizes[0] / 64;
    const int E = in_sizes[1] / 8;
    const int* row = ei;
    const int* col = ei + E;
    const int NBUCK = (N + 127) / 128;
    const int EB = (E + 8191) / 8192;

    // ---- workspace carve (de-aliased two-chain layout)
    auto au = [](size_t v) { return (v + 255) & ~(size_t)255; };
    char* p = (char*)d_ws;
    int* cnt = (int*)p;        p += au((size_t)N * 4);
    int* rowptr = (int*)p;     p += au((size_t)(N + 1) * 4);
    int* bbase = (int*)p;      p += au(513 * 4);
    int* bwp = (int*)p;        p += au(512 * 4);
    float* w12_0 = (float*)p;  p += au(512 * 4);
    float* w12_1 = (float*)p;  p += au(4096 * 4);
    float* w12_2 = (float*)p;  p += au(2048 * 4);
    float* w12_3 = (float*)p;  p += au(1024 * 4);
    float* cbuf = (float*)p;   p += au(544 * 4);
    int* bpart = (int*)p;      p += au((size_t)EB * 512 * 4);
    int* rowsA = (int*)p;      p += au((size_t)E * 4);
    int* eidsA = (int*)p;      p += au((size_t)E * 4);
    unsigned short* T = (unsigned short*)p; p += au((size_t)N * 64 * 2);  // bf16 hl table
    float* R = (float*)p;      p += au((size_t)N * 64 * 4);               // hr
    float* H1 = (float*)p;     p += au((size_t)N * 64 * 4);
    float* H2 = (float*)p;     p += au((size_t)N * 64 * 4);
    float* S1 = (float*)p;     p += au((size_t)N * 64 * 4);               // sd1 (also tmp)
    float* S2 = (float*)p;     p += au((size_t)N * 64 * 4);               // sd2
    float* S3 = (float*)p;     p += au((size_t)N * 32 * 4);               // sd3
    float* sd0 = (float*)p;    p += au((size_t)N * 8 * 4);
    unsigned short* h3b = (unsigned short*)p; p += au((size_t)N * 32 * 2);
    float* ddot = (float*)p;   p += au((size_t)N * 4);

    int2* tmp = (int2*)S1;  // E*8 = 6.4MB <= S1's 12.8MB; tmp dead before S1 first write (D5)

    const int G0 = (N + 31) / 32;
    const int G2 = (N + 63) / 64;
    const int G3 = (N + 63) / 64;
    const int E0 = (N + 15) / 16;
    const int E2 = (N + 31) / 32;
    const int NB = (N + 3) / 4;

    // ---- D1: atomic-free bucket counts + w12 + parallel consts
    count_w12c_k<<<EB + 169, 1024, 0, stream>>>(
        col, bpart, E, EB, e_w1[0], e_w2[0], w12_0, e_w1[1], e_w2[1], w12_1, e_w1[2], e_w2[2],
        w12_2, e_w1[3], e_w2[3], w12_3, e_b1[0], e_b2[0], e_b1[1], e_b2[1], e_b1[2], e_b2[2],
        e_b1[3], e_b2[3], fcw, cbuf);
    // ---- D2-D3: scan + scatter
    bucket_scan_k<<<1, 512, 0, stream>>>(bpart, bbase, bwp, NBUCK, E, EB);
    bucket_scatter_k<<<EB, 1024, 0, stream>>>(row, col, bwp, tmp, E);
    // ---- D4: CSR finalize ∥ SAGE L0 gemm (x -> T,R)
    csr_gemm0_k<<<NBUCK + G0, 256, 0, stream>>>(tmp, bbase, rowptr, cnt, rowsA, eidsA, N, E,
                                                NBUCK, x, s_wl[0], s_wr[0], s_bl[0], T, R);
    // ---- D5: SAGE L0 aggr (T,R -> H1) ∥ edge_aggr8 (dis -> sd0; zero S1)
    ag64_ea8_k<<<2 * NB, 256, 0, stream>>>(T, R, rowptr, rowsA, H1, dis, eidsA, sd0, S1, N, NB);
    // ---- D6: gemm L1 (H1 -> T,R) ∥ esc0 (sd0 -> scatter S1; zero S2)
    g64_esc0_k<<<G0 + E0, 256, 0, stream>>>(H1, s_wl[1], s_wr[1], s_bl[1], T, R, sd0, cnt, w12_0,
                                            cbuf + 192, cbuf + 192, e_b2[0], cbuf + 0, col, S1,
                                            S2, N, G0, E0);
    // ---- D7: SAGE L1 aggr (T,R -> H2) ∥ esc1 (S1 -> scatter S2; zero S3)
    ag64_esc1_k<<<NB + E0, 256, 0, stream>>>(T, R, rowptr, rowsA, H2, S1, cnt, w12_1, cbuf + 320,
                                             cbuf + 256, e_b2[1], cbuf + 64, col, S2, S3, N, NB,
                                             E0);
    // ---- D8: gemm L2 (H2 -> T,R 32w) ∥ esc2 (S2 -> scatter S3)
    g32_esc2_k<<<G2 + E2, 256, 0, stream>>>(H2, s_wl[2], s_wr[2], s_bl[2], T, R, S2, cnt, w12_2,
                                            cbuf + 416, cbuf + 384, e_b2[2], cbuf + 128, col, S3,
                                            N, G2, E2);
    // ---- D9: SAGE L2 aggr (T,R -> H1 32w f32) ∥ edot (S3 -> ddot)
    ag32_edot_k<<<NB + E2, 256, 0, stream>>>(T, R, rowptr, rowsA, H1, S3, cnt, w12_3, cbuf + 480,
                                             cbuf + 448, e_b2[3], fcw, ddot, N, NB);
    // ---- D10: gemm L3 (H1 -> T,R 32w)
    gemm2_32_k<<<G3, 256, 0, stream>>>(H1, s_wl[3], s_wr[3], s_bl[3], T, R, N);
    // ---- D11: SAGE L3 aggr -> h3b (bf16)
    ag32bf_k<<<NB, 256, 0, stream>>>(T, R, rowptr, rowsA, h3b, N);
    // ---- D12: final per-edge output, CSR-ordered
    final_csr_k<<<NB, 256, 0, stream>>>(h3b, ddot, cbuf, rowptr, rowsA, eidsA, fcw, fcb,
                                        (float*)d_out, N);
}